// Round 6
// baseline (699.140 us; speedup 1.0000x reference)
//
#include <hip/hip_runtime.h>
#include <hip/hip_bf16.h>
#include <type_traits>

#define NN 50000
#define NP 50048   // NN padded to 64*782 (and 128*391)
#define EE 800000
#define TT 3
#define ED 64
#define NS 23
#define MD 87
#define HH 200
#define NMOL 2048
#define RD 256

#define SW 232     // per-wave LDS act row stride (shorts)
#define NPB2 512   // colstats partial blocks
#define SNB ((NN + 255) / 256)  // 196 scan blocks

typedef __attribute__((ext_vector_type(8))) short short8b;
typedef __attribute__((ext_vector_type(4))) float f32x4;

template <int V> using ic = std::integral_constant<int, V>;

// ---- bf16 helpers ----
__device__ __forceinline__ unsigned short f2bf(float f) {
  unsigned u = __float_as_uint(f);
  return (unsigned short)((u + 0x7fffu + ((u >> 16) & 1u)) >> 16);
}
__device__ __forceinline__ float ubf2f(unsigned short h) {
  return __uint_as_float(((unsigned)h) << 16);
}
// interleaved pair in one u32: low16 = hi-bf16, high16 = lo-bf16 (fp32-equivalent)
__device__ __forceinline__ float bfp2f(unsigned p) {
  return __uint_as_float(p << 16) + __uint_as_float(p & 0xffff0000u);
}
__device__ __forceinline__ unsigned packsplit(float v) {
  unsigned short h = f2bf(v);
  unsigned short l = f2bf(v - ubf2f(h));
  return (unsigned)h | ((unsigned)l << 16);
}

// async global->LDS: 16B per lane, lane i lands at ldsbase + 16*i (HW rule)
__device__ __forceinline__ void gl2lds16(const short* g, short* l) {
  __builtin_amdgcn_global_load_lds(
      (const __attribute__((address_space(1))) unsigned int*)g,
      (__attribute__((address_space(3))) unsigned int*)l, 16, 0, 0);
}

// ---------------- weight prep: fp32 [T][K][N] -> PACKED fragment-major planes -----
// Packed layout: per (tile of 16 n-rows, kblk of 32 cols): 1024 shorts =
// [512 hi][512 lo], lane-linear (slot = lane*8+e, lane = quad*16+ln,
// n = tile*16+ln, k = kblk*32+quad*8+e). B-frag load = ONE coalesced 1KB burst.
struct WD { const float* src; short* dst; int K, N, Kpad, Npad, T; };
struct WDs { WD d[5]; };

__global__ __launch_bounds__(256) void wprep_kernel(WDs W) {
  WD w = W.d[blockIdx.y];
  int KB = w.Kpad >> 5, NT = w.Npad >> 4;
  int per = w.Npad * w.Kpad;  // == NT*KB*512
  int total = w.T * per;
  for (int idx = blockIdx.x * 256 + threadIdx.x; idx < total; idx += gridDim.x * 256) {
    int t = idx / per;
    int r = idx - t * per;
    int e = r & 7, lane = (r >> 3) & 63;
    int blk = r >> 9;
    int kb = blk % KB, tile = blk / KB;
    int ln = lane & 15, quad = lane >> 4;
    int n = tile * 16 + ln, k = kb * 32 + quad * 8 + e;
    float v = 0.f;
    if (k < w.K && n < w.N) v = w.src[((size_t)t * w.K + k) * w.N + n];
    unsigned short h = f2bf(v);
    unsigned short l = f2bf(v - ubf2f(h));
    size_t base = ((size_t)(t * NT + tile) * KB + kb) * 1024;
    w.dst[base + lane * 8 + e] = (short)h;
    w.dst[base + 512 + lane * 8 + e] = (short)l;
  }
}

// ---------------- BN-folded layer-1 weight scale (packed output) ----------------
__global__ __launch_bounds__(256) void wscale_kernel(const float* __restrict__ wsrc,
                                                     const float* __restrict__ na,
                                                     const float* __restrict__ nb,
                                                     const float* __restrict__ bsrc,
                                                     int K, int Kpad,
                                                     short* __restrict__ wsp,
                                                     float* __restrict__ bc) {
  int n = blockIdx.x;   // 0..207
  int k = threadIdx.x;  // 0..255
  int KB = Kpad >> 5;
  int tile = n >> 4, ln = n & 15;
  float contrib = 0.f;
  if (k < Kpad) {
    float v = 0.f;
    if (n < HH && k < K) {
      float w = wsrc[(size_t)k * HH + n];
      v = na[k] * w;
      contrib = nb[k] * w;
    }
    unsigned short h = f2bf(v);
    unsigned short l = f2bf(v - ubf2f(h));
    int kb = k >> 5, quad = (k & 31) >> 3, e = k & 7;
    int lane = quad * 16 + ln;
    size_t base = ((size_t)tile * KB + kb) * 1024;
    wsp[base + lane * 8 + e] = (short)h;
    wsp[base + 512 + lane * 8 + e] = (short)l;
  }
  __shared__ float sh[256];
  sh[k] = contrib;
  __syncthreads();
  for (int off = 128; off > 0; off >>= 1) {
    if (k < off) sh[k] += sh[k + off];
    __syncthreads();
  }
  if (k == 0) bc[n] = (n < HH ? bsrc[n] : 0.f) + sh[0];
}

// ---------------- embedding -> x slice 0 (pair + row plane + slice plane) ----
__global__ __launch_bounds__(256) void emb_kernel(const int* __restrict__ z,
                                                  const float* __restrict__ emb,
                                                  unsigned* __restrict__ xp,
                                                  short* __restrict__ xq,
                                                  short* __restrict__ xqs) {
  int idx = blockIdx.x * 256 + threadIdx.x;
  if (idx >= NN * ED) return;
  int i = idx >> 6, d = idx & 63;
  unsigned pk = packsplit(emb[z[i] * ED + d]);
  xp[(size_t)i * RD + d] = pk;
  short h = (short)(pk & 0xffffu);
  xq[(size_t)i * RD + d] = h;
  xqs[(size_t)i * ED + d] = h;  // slice 0
}

// ---------------- CSR build ----------------
__global__ __launch_bounds__(256) void hist_kernel(const int* __restrict__ src,
                                                   int* __restrict__ deg) {
  int e = blockIdx.x * 256 + threadIdx.x;
  if (e < EE) atomicAdd(&deg[src[e]], 1);
}

// 3-stage parallel exclusive scan of deg[0..NN)
__global__ __launch_bounds__(256) void scanA_kernel(const int* __restrict__ deg,
                                                    int* __restrict__ Psum) {
  int i = blockIdx.x * 256 + threadIdx.x;
  int v = (i < NN) ? deg[i] : 0;
#pragma unroll
  for (int off = 32; off > 0; off >>= 1) v += __shfl_down(v, off, 64);
  __shared__ int ws[4];
  if ((threadIdx.x & 63) == 0) ws[threadIdx.x >> 6] = v;
  __syncthreads();
  if (threadIdx.x == 0) Psum[blockIdx.x] = ws[0] + ws[1] + ws[2] + ws[3];
}

__global__ __launch_bounds__(256) void scanB_kernel(const int* __restrict__ Psum,
                                                    int* __restrict__ Poff) {
  __shared__ int sh[256];
  int t = threadIdx.x;
  int v = (t < SNB) ? Psum[t] : 0;
  sh[t] = v;
  __syncthreads();
  for (int off = 1; off < 256; off <<= 1) {
    int u = (t >= off) ? sh[t - off] : 0;
    __syncthreads();
    sh[t] += u;
    __syncthreads();
  }
  if (t < SNB) Poff[t] = sh[t] - v;  // exclusive
}

__global__ __launch_bounds__(256) void scanC_kernel(const int* __restrict__ deg,
                                                    const int* __restrict__ Poff,
                                                    int* __restrict__ offs,
                                                    int* __restrict__ cursor) {
  __shared__ int sh[256];
  int t = threadIdx.x;
  int i = blockIdx.x * 256 + t;
  int v = (i < NN) ? deg[i] : 0;
  sh[t] = v;
  __syncthreads();
  for (int off = 1; off < 256; off <<= 1) {
    int u = (t >= off) ? sh[t - off] : 0;
    __syncthreads();
    sh[t] += u;
    __syncthreads();
  }
  int excl = Poff[blockIdx.x] + sh[t] - v;
  if (i < NN) {
    offs[i] = excl;
    cursor[i] = excl;
    if (i == NN - 1) offs[NN] = excl + v;
  }
}

__global__ __launch_bounds__(256) void scatter_kernel(const int* __restrict__ src,
                                                      const int* __restrict__ snk,
                                                      const float* __restrict__ dist,
                                                      int* __restrict__ cursor,
                                                      int* __restrict__ ssink,
                                                      float* __restrict__ sdist) {
  int e = blockIdx.x * 256 + threadIdx.x;
  if (e >= EE) return;
  int p = atomicAdd(&cursor[src[e]], 1);
  ssink[p] = snk[e];
  sdist[p] = dist[e];
}

// ---------------- message gather: one wave per node ----------------
template <bool RBF>
__global__ __launch_bounds__(256) void gather_kernel(const int* __restrict__ offs,
                                                     const int* __restrict__ ssink,
                                                     const float* __restrict__ sdist,
                                                     const short* __restrict__ xqs,
                                                     short* __restrict__ mh) {
  int node = blockIdx.x * 4 + (threadIdx.x >> 6);
  int lane = threadIdx.x & 63;
  if (node >= NN) return;
  float shift = (float)(0.8 + 0.1 * (double)lane);
  int e0 = offs[node], e1 = offs[node + 1];
  float ax0 = 0.f, ax1 = 0.f, ar0 = 0.f, ar1 = 0.f;
  int j = e0;
  for (; j + 4 <= e1; j += 4) {
    int s0 = ssink[j], s1 = ssink[j + 1], s2 = ssink[j + 2], s3 = ssink[j + 3];
    float x0 = ubf2f((unsigned short)xqs[(size_t)s0 * ED + lane]);
    float x1 = ubf2f((unsigned short)xqs[(size_t)s1 * ED + lane]);
    float x2 = ubf2f((unsigned short)xqs[(size_t)s2 * ED + lane]);
    float x3 = ubf2f((unsigned short)xqs[(size_t)s3 * ED + lane]);
    ax0 += x0 + x2;
    ax1 += x1 + x3;
    if (RBF && lane < NS) {
      float d0 = sdist[j], d1 = sdist[j + 1], d2 = sdist[j + 2], d3 = sdist[j + 3];
      float u0 = d0 - shift, u1 = d1 - shift, u2 = d2 - shift, u3 = d3 - shift;
      ar0 += __expf(-u0 * u0) + __expf(-u2 * u2);
      ar1 += __expf(-u1 * u1) + __expf(-u3 * u3);
    }
  }
  for (; j < e1; j++) {
    int s = ssink[j];
    ax0 += ubf2f((unsigned short)xqs[(size_t)s * ED + lane]);
    if (RBF && lane < NS) {
      float u = sdist[j] - shift;
      ar0 += __expf(-u * u);
    }
  }
  float accx = ax0 + ax1;
  if (RBF && lane < NS) mh[(size_t)node * 96 + lane] = (short)f2bf(ar0 + ar1);
  if (RBF && lane >= NS && lane < 32) mh[(size_t)node * 96 + 64 + lane] = 0;
  mh[(size_t)node * 96 + NS + lane] = (short)f2bf(accx);
}

// ---------------- batchnorm stats on bf16 planes (vectorized, 512 blocks) ----
template <int LD>
__global__ __launch_bounds__(256) void colstats_s16_kernel(const short* __restrict__ X,
                                                           float* __restrict__ P) {
  constexpr int CG = LD / 8;     // 8-col groups
  constexpr int RPB = 256 / CG;
  const int t = threadIdx.x;
  const int cg = t % CG, rin = t / CG;
  float s[8] = {0, 0, 0, 0, 0, 0, 0, 0}, q[8] = {0, 0, 0, 0, 0, 0, 0, 0};
  if (rin < RPB) {
    for (int r = blockIdx.x * RPB + rin; r < NN; r += gridDim.x * RPB) {
      union { uint4 v; short e[8]; } u;
      u.v = *(const uint4*)(X + (size_t)r * LD + cg * 8);
#pragma unroll
      for (int e = 0; e < 8; e++) {
        float f = ubf2f((unsigned short)u.e[e]);
        s[e] += f;
        q[e] += f * f;
      }
    }
  }
  __shared__ float sh[256][16];
#pragma unroll
  for (int e = 0; e < 8; e++) { sh[t][e] = s[e]; sh[t][8 + e] = q[e]; }
  __syncthreads();
  if (rin == 0) {
    for (int rr = 1; rr < RPB; rr++) {
      const float* o = sh[rr * CG + cg];
#pragma unroll
      for (int e = 0; e < 8; e++) { s[e] += o[e]; q[e] += o[8 + e]; }
    }
    float* Pb = P + blockIdx.x * 512;
#pragma unroll
    for (int e = 0; e < 8; e++) {
      Pb[cg * 8 + e] = s[e];
      Pb[256 + cg * 8 + e] = q[e];
    }
  }
}

// ---------------- batchnorm stats: stage 2 (one block per column) ------------
__global__ __launch_bounds__(256) void bnfinal2_kernel(const float* __restrict__ P, int nblk,
                                                       const float* __restrict__ g,
                                                       const float* __restrict__ b, int ncols,
                                                       float* __restrict__ na,
                                                       float* __restrict__ nb) {
  int c = blockIdx.x;
  int t = threadIdx.x;
  float s = 0.f, q = 0.f;
  for (int i = t; i < nblk; i += 256) {
    s += P[i * 512 + c];
    q += P[i * 512 + 256 + c];
  }
#pragma unroll
  for (int off = 32; off > 0; off >>= 1) {
    s += __shfl_down(s, off, 64);
    q += __shfl_down(q, off, 64);
  }
  __shared__ float ws[4], wq[4];
  if ((t & 63) == 0) { ws[t >> 6] = s; wq[t >> 6] = q; }
  __syncthreads();
  if (t == 0) {
    s = ws[0] + ws[1] + ws[2] + ws[3];
    q = wq[0] + wq[1] + wq[2] + wq[3];
    if (c < ncols) {
      float mean = s / (float)NN;
      float var = q / (float)NN - mean * mean;
      float a = g[c] * rsqrtf(var + 1e-5f);
      na[c] = a;
      nb[c] = b[c] - mean * a;
    } else {
      na[c] = 0.f;
      nb[c] = 0.f;
    }
  }
}

// ============ V0 control: exact R22 DMA-staged kernel (measured 70.9us) ======
template <bool READOUT>
__global__ __launch_bounds__(256, 2) void fused_dma_kernel(
    const short* __restrict__ Agh,
    const short* __restrict__ W1p, const short* __restrict__ W2p,
    const short* __restrict__ W3p, const short* __restrict__ W4p,
    const float* __restrict__ b1, const float* __restrict__ b2,
    const float* __restrict__ b3, const float* __restrict__ b4,
    unsigned* __restrict__ xp, short* __restrict__ xq, short* __restrict__ xqs,
    int t, const float* __restrict__ w4ro, const int* __restrict__ mol,
    float* __restrict__ out) {
  __shared__ short ldsA[4 * 16 * SW];
  __shared__ short ldsB[2][13 * 512];
  constexpr int GLDA = READOUT ? RD : 96;
  constexpr int KB1 = READOUT ? 8 : 3;
  const int tid = threadIdx.x;
  const int wave = tid >> 6, lane = tid & 63, ln = lane & 15, quad = lane >> 4;
  const int q8 = quad * 8;
  const int bm = blockIdx.x * 64 + wave * 16;
  short* ldsW = ldsA + wave * (16 * SW);
  const short* aRow = ldsW + ln * SW;

#pragma unroll
  for (int p = 0; p < 6; p++) {
    int idx = p * 64 + lane;
    ldsW[(idx / 24) * SW + 208 + (idx % 24)] = 0;
  }

  f32x4 acc[13];
  short8b a[7];

  auto stage = [&](auto ntt, auto kbt, const short* __restrict__ Wp, int s, int buf) {
    constexpr int NT = decltype(ntt)::value;
    constexpr int KB = decltype(kbt)::value;
    const int kb = (s < KB) ? s : s - KB;
    const int plane = (s < KB) ? 0 : 512;
    for (int tile = wave; tile < NT; tile += 4)
      gl2lds16(Wp + (size_t)(tile * KB + kb) * 1024 + plane + lane * 8,
               ldsB[buf] + tile * 512);
  };

  auto runlayer = [&](auto ntt, auto kbt, auto tt, const short8b* af,
                      const short* __restrict__ Wp) {
    constexpr int NT = decltype(ntt)::value;
    constexpr int KB = decltype(kbt)::value;
    constexpr int TERMS = decltype(tt)::value;
    constexpr int NSL = KB * TERMS;
#pragma unroll
    for (int j = 0; j < NT; j++) acc[j] = (f32x4){0.f, 0.f, 0.f, 0.f};
    stage(ntt, kbt, Wp, 0, 0);
    __syncthreads();
#pragma unroll
    for (int s = 0; s < NSL; s++) {
      if (s + 1 < NSL) stage(ntt, kbt, Wp, s + 1, (s + 1) & 1);
      const int kb = (s < KB) ? s : s - KB;
      short8b bh[NT];
#pragma unroll
      for (int j = 0; j < NT; j++)
        bh[j] = *(const short8b*)(ldsB[s & 1] + j * 512 + lane * 8);
#pragma unroll
      for (int j = 0; j < NT; j++)
        acc[j] = __builtin_amdgcn_mfma_f32_16x16x32_bf16(af[kb], bh[j], acc[j], 0, 0, 0);
      __syncthreads();
    }
  };

  auto epi = [&](auto ntt, const float* __restrict__ bias) {
    constexpr int NT = decltype(ntt)::value;
#pragma unroll
    for (int j = 0; j < NT; j++) {
      int colg = j * 16 + ln;
      float bb = (colg < HH) ? bias[colg] : 0.f;
#pragma unroll
      for (int r = 0; r < 4; r++)
        ldsW[(quad * 4 + r) * SW + colg] = (short)f2bf(fmaxf(acc[j][r] + bb, 0.f));
    }
  };
  auto loadA = [&]() {
#pragma unroll
    for (int kb = 0; kb < 7; kb++)
      a[kb] = *(const short8b*)(aRow + kb * 32 + q8);
  };

  {
    short8b a1[KB1];
#pragma unroll
    for (int kb = 0; kb < KB1; kb++)
      a1[kb] = *(const short8b*)(Agh + (size_t)(bm + ln) * GLDA + kb * 32 + q8);
    runlayer(ic<13>{}, ic<KB1>{}, ic<2>{}, a1, W1p);
    epi(ic<13>{}, b1);
  }
  loadA();
  runlayer(ic<13>{}, ic<7>{}, ic<1>{}, a, W2p);
  epi(ic<13>{}, b2);
  loadA();
  runlayer(ic<13>{}, ic<7>{}, ic<1>{}, a, W3p);
  epi(ic<13>{}, b3);
  loadA();

  if constexpr (!READOUT) {
    runlayer(ic<4>{}, ic<7>{}, ic<2>{}, a, W4p);
#pragma unroll
    for (int j = 0; j < 4; j++) {
      int colg = j * 16 + ln;
      float bb = b4[colg];
#pragma unroll
      for (int r = 0; r < 4; r++) {
        int grow = bm + quad * 4 + r;
        if (grow < NN) {
          size_t base = (size_t)grow * RD;
          float oldv = bfp2f(xp[base + (size_t)t * ED + colg]);
          unsigned pk = packsplit(oldv + 0.1f * (acc[j][r] + bb));
          xp[base + (size_t)(t + 1) * ED + colg] = pk;
          short h = (short)(pk & 0xffffu);
          xq[base + (size_t)(t + 1) * ED + colg] = h;
          xqs[(size_t)(t + 1) * NN * ED + (size_t)grow * ED + colg] = h;
        }
      }
    }
  } else {
    float s = 0.f;
#pragma unroll
    for (int kb = 0; kb < 7; kb++)
      if (kb * 32 + q8 < HH)
#pragma unroll
        for (int e = 0; e < 8; e++)
          s += ubf2f((unsigned short)a[kb][e]) * w4ro[kb * 32 + q8 + e];
    s += __shfl_xor(s, 16, 64);
    s += __shfl_xor(s, 32, 64);
    int grow = bm + ln;
    if (lane < 16 && grow < NN) atomicAdd(&out[mol[grow]], s + b4[0]);
  }
}

// ============ Reg-staged variant (T14 async-split; no global_load_lds) =======
// Per slice: issue slice s+1 global->REG loads; MFMAs of slice s (hides the
// L2 latency); ds_write regs -> buf[(s+1)&1]; one __syncthreads (vmcnt already
// drained by consumption). WAVES=4 (64 rows) or 8 (128 rows, halves the
// per-CU block-generation count).
template <bool READOUT, int WAVES>
__global__ __launch_bounds__(WAVES * 64, (WAVES == 4) ? 2 : 1) void fused_reg_kernel(
    const short* __restrict__ Agh,
    const short* __restrict__ W1p, const short* __restrict__ W2p,
    const short* __restrict__ W3p, const short* __restrict__ W4p,
    const float* __restrict__ b1, const float* __restrict__ b2,
    const float* __restrict__ b3, const float* __restrict__ b4,
    unsigned* __restrict__ xp, short* __restrict__ xq, short* __restrict__ xqs,
    int t, const float* __restrict__ w4ro, const int* __restrict__ mol,
    float* __restrict__ out) {
  __shared__ short act[WAVES * 16 * SW];
  __shared__ short bufW[2][13 * 512];
  constexpr int GLDA = READOUT ? RD : 96;
  constexpr int KB1 = READOUT ? 8 : 3;
  constexpr int TPW = (13 + WAVES - 1) / WAVES;  // staged tiles per wave
  const int tid = threadIdx.x;
  const int wave = tid >> 6, lane = tid & 63, ln = lane & 15, quad = lane >> 4;
  const int q8 = quad * 8;
  const int bm = blockIdx.x * (WAVES * 16) + wave * 16;
  short* ldsW = act + wave * (16 * SW);
  const short* aRow = ldsW + ln * SW;

  // zero k-pad cols [208,232) of own plane
#pragma unroll
  for (int p = 0; p < 6; p++) {
    int idx = p * 64 + lane;
    ldsW[(idx / 24) * SW + 208 + (idx % 24)] = 0;
  }

  f32x4 acc[13];
  short8b a[(KB1 > 7) ? KB1 : 7];

  auto runlayer = [&](auto ntt, auto kbt, auto tt, const short8b* af,
                      const short* __restrict__ Wp) {
    constexpr int NT = decltype(ntt)::value;
    constexpr int KB = decltype(kbt)::value;
    constexpr int TERMS = decltype(tt)::value;
    constexpr int NSL = KB * TERMS;
#pragma unroll
    for (int j = 0; j < NT; j++) acc[j] = (f32x4){0.f, 0.f, 0.f, 0.f};
    short8b rs[TPW];
    // prologue: slice 0 -> buf 0 (kb=0, plane=0)
#pragma unroll
    for (int j = 0; j < TPW; j++) {
      int tile = wave + WAVES * j;
      if (tile < NT)
        rs[j] = *(const short8b*)(Wp + (size_t)(tile * KB) * 1024 + lane * 8);
    }
#pragma unroll
    for (int j = 0; j < TPW; j++) {
      int tile = wave + WAVES * j;
      if (tile < NT) *(short8b*)(&bufW[0][tile * 512 + lane * 8]) = rs[j];
    }
    __syncthreads();
#pragma unroll
    for (int s = 0; s < NSL; s++) {
      if (s + 1 < NSL) {
        const int kb2 = (TERMS == 2) ? ((s + 1) >> 1) : (s + 1);
        const int pl2 = (TERMS == 2) ? (((s + 1) & 1) << 9) : 0;
#pragma unroll
        for (int j = 0; j < TPW; j++) {
          int tile = wave + WAVES * j;
          if (tile < NT)
            rs[j] = *(const short8b*)(Wp + (size_t)(tile * KB + kb2) * 1024 +
                                      pl2 + lane * 8);
        }
      }
      const int kb = (TERMS == 2) ? (s >> 1) : s;
      const short* bw = &bufW[s & 1][0];
#pragma unroll
      for (int j = 0; j < NT; j++) {
        short8b b = *(const short8b*)(bw + j * 512 + lane * 8);
        acc[j] = __builtin_amdgcn_mfma_f32_16x16x32_bf16(af[kb], b, acc[j], 0, 0, 0);
      }
      if (s + 1 < NSL) {
        short* bw2 = &bufW[(s + 1) & 1][0];
#pragma unroll
        for (int j = 0; j < TPW; j++) {
          int tile = wave + WAVES * j;
          if (tile < NT) *(short8b*)(bw2 + tile * 512 + lane * 8) = rs[j];
        }
      }
      __syncthreads();
    }
  };

  auto epi = [&](auto ntt, const float* __restrict__ bias) {
    constexpr int NT = decltype(ntt)::value;
#pragma unroll
    for (int j = 0; j < NT; j++) {
      int colg = j * 16 + ln;
      float bb = (colg < HH) ? bias[colg] : 0.f;
#pragma unroll
      for (int r = 0; r < 4; r++)
        ldsW[(quad * 4 + r) * SW + colg] = (short)f2bf(fmaxf(acc[j][r] + bb, 0.f));
    }
  };
  auto loadA = [&]() {
#pragma unroll
    for (int kb = 0; kb < 7; kb++)
      a[kb] = *(const short8b*)(aRow + kb * 32 + q8);
  };

  // ---- L1: A from global ----
#pragma unroll
  for (int kb = 0; kb < KB1; kb++)
    a[kb] = *(const short8b*)(Agh + (size_t)(bm + ln) * GLDA + kb * 32 + q8);
  runlayer(ic<13>{}, ic<KB1>{}, ic<2>{}, a, W1p);
  epi(ic<13>{}, b1);   // own plane only; next loadA same wave -> no barrier

  loadA();
  runlayer(ic<13>{}, ic<7>{}, ic<1>{}, a, W2p);
  epi(ic<13>{}, b2);

  loadA();
  runlayer(ic<13>{}, ic<7>{}, ic<1>{}, a, W3p);
  epi(ic<13>{}, b3);

  loadA();

  if constexpr (!READOUT) {
    runlayer(ic<4>{}, ic<7>{}, ic<2>{}, a, W4p);
#pragma unroll
    for (int j = 0; j < 4; j++) {
      int colg = j * 16 + ln;
      float bb = b4[colg];
#pragma unroll
      for (int r = 0; r < 4; r++) {
        int grow = bm + quad * 4 + r;
        if (grow < NN) {
          size_t base = (size_t)grow * RD;
          float oldv = bfp2f(xp[base + (size_t)t * ED + colg]);
          unsigned pk = packsplit(oldv + 0.1f * (acc[j][r] + bb));
          xp[base + (size_t)(t + 1) * ED + colg] = pk;
          short h = (short)(pk & 0xffffu);
          xq[base + (size_t)(t + 1) * ED + colg] = h;
          xqs[(size_t)(t + 1) * NN * ED + (size_t)grow * ED + colg] = h;
        }
      }
    }
  } else {
    // h3 in a[]: a[kb][e] = h3[row=ln][k=kb*32+q8+e]; cols >=200 zero
    float s = 0.f;
#pragma unroll
    for (int kb = 0; kb < 7; kb++)
      if (kb * 32 + q8 < HH)
#pragma unroll
        for (int e = 0; e < 8; e++)
          s += ubf2f((unsigned short)a[kb][e]) * w4ro[kb * 32 + q8 + e];
    s += __shfl_xor(s, 16, 64);
    s += __shfl_xor(s, 32, 64);
    int grow = bm + ln;
    if (lane < 16 && grow < NN) atomicAdd(&out[mol[grow]], s + b4[0]);
  }
}

// ---------------- host launcher ----------------
extern "C" void kernel_launch(void* const* d_in, const int* in_sizes, int n_in,
                              void* d_out, int out_size, void* d_ws, size_t ws_size,
                              hipStream_t stream) {
  const int* z_i = (const int*)d_in[0];
  const int* e_src = (const int*)d_in[1];
  const int* e_snk = ((const int*)d_in[1]) + EE;
  const float* dist = (const float*)d_in[2];
  const int* mol = (const int*)d_in[3];
  const float* emb = (const float*)d_in[4];
  const float* up_bn_g = (const float*)d_in[5];
  const float* up_bn_b = (const float*)d_in[6];
  const float* up_w1 = (const float*)d_in[7];
  const float* up_b1 = (const float*)d_in[8];
  const float* up_w2 = (const float*)d_in[9];
  const float* up_b2 = (const float*)d_in[10];
  const float* up_w3 = (const float*)d_in[11];
  const float* up_b3 = (const float*)d_in[12];
  const float* up_w4 = (const float*)d_in[13];
  const float* up_b4 = (const float*)d_in[14];
  const float* ro_bn_g = (const float*)d_in[15];
  const float* ro_bn_b = (const float*)d_in[16];
  const float* ro_w1 = (const float*)d_in[17];
  const float* ro_b1 = (const float*)d_in[18];
  const float* ro_w2 = (const float*)d_in[19];
  const float* ro_b2 = (const float*)d_in[20];
  const float* ro_w3 = (const float*)d_in[21];
  const float* ro_b3 = (const float*)d_in[22];
  const float* ro_w4 = (const float*)d_in[23];
  const float* ro_b4 = (const float*)d_in[24];
  float* out = (float*)d_out;

  char* p = (char*)d_ws;
  auto alloc = [&](size_t bytes) {
    void* r = (void*)p;
    p += (bytes + 255) & ~(size_t)255;
    return r;
  };
  unsigned* x_p = (unsigned*)alloc((size_t)NN * RD * 4);     // fp32-equiv pair
  short* x_q = (short*)alloc((size_t)NP * RD * 2);           // x hi plane (row-major)
  short* x_qs = (short*)alloc((size_t)(TT + 1) * NN * ED * 2);  // x hi SLICE-major (gather)
  short* mh = (short*)alloc((size_t)NP * 96 * 2);            // raw m hi plane
  int* ssink = (int*)alloc((size_t)EE * 4);
  float* sdist = (float*)alloc((size_t)EE * 4);
  int* offs = (int*)alloc((size_t)(NN + 1) * 4);
  int* deg = (int*)alloc((size_t)NN * 4);
  int* cursor = (int*)alloc((size_t)NN * 4);
  int* Psum = (int*)alloc((size_t)SNB * 4);
  int* Poff = (int*)alloc((size_t)SNB * 4);
  float* P = (float*)alloc((size_t)NPB2 * 512 * 4);
  float* na = (float*)alloc(256 * 4);
  float* nb = (float*)alloc(256 * 4);
  float* b1c = (float*)alloc(208 * 4);
  // packed layer-1 (BN-scaled per pass / readout)
  short* w1sp = (short*)alloc((size_t)13 * 3 * 1024 * 2);
  short* r1sp = (short*)alloc((size_t)13 * 8 * 1024 * 2);
  // packed static weights
  short* w2p = (short*)alloc((size_t)TT * 13 * 7 * 1024 * 2);
  short* w3p = (short*)alloc((size_t)TT * 13 * 7 * 1024 * 2);
  short* w4p = (short*)alloc((size_t)TT * 4 * 7 * 1024 * 2);
  short* r2p = (short*)alloc((size_t)13 * 7 * 1024 * 2);
  short* r3p = (short*)alloc((size_t)13 * 7 * 1024 * 2);

  hipMemsetAsync(deg, 0, (size_t)NN * 4, stream);
  hipMemsetAsync(out, 0, (size_t)NMOL * 4, stream);

  WDs descs;
  descs.d[0] = {up_w2, w2p, HH, HH, 224, 208, TT};
  descs.d[1] = {up_w3, w3p, HH, HH, 224, 208, TT};
  descs.d[2] = {up_w4, w4p, HH, ED, 224, 64, TT};
  descs.d[3] = {ro_w2, r2p, HH, HH, 224, 208, 1};
  descs.d[4] = {ro_w3, r3p, HH, HH, 224, 208, 1};
  wprep_kernel<<<dim3(546, 5), 256, 0, stream>>>(descs);

  emb_kernel<<<(NN * ED + 255) / 256, 256, 0, stream>>>(z_i, emb, x_p, x_q, x_qs);
  hist_kernel<<<(EE + 255) / 256, 256, 0, stream>>>(e_src, deg);
  scanA_kernel<<<SNB, 256, 0, stream>>>(deg, Psum);
  scanB_kernel<<<1, 256, 0, stream>>>(Psum, Poff);
  scanC_kernel<<<SNB, 256, 0, stream>>>(deg, Poff, offs, cursor);
  scatter_kernel<<<(EE + 255) / 256, 256, 0, stream>>>(e_src, e_snk, dist, cursor, ssink, sdist);

  const int gM64 = NP / 64;    // 782
  const int gM128 = NP / 128;  // 391

  for (int t = 0; t < TT; t++) {
    if (t == 0)
      gather_kernel<true><<<(NN + 3) / 4, 256, 0, stream>>>(
          offs, ssink, sdist, x_qs, mh);
    else
      gather_kernel<false><<<(NN + 3) / 4, 256, 0, stream>>>(
          offs, ssink, sdist, x_qs + (size_t)t * NN * ED, mh);
    colstats_s16_kernel<96><<<NPB2, 256, 0, stream>>>(mh, P);
    bnfinal2_kernel<<<256, 256, 0, stream>>>(P, NPB2, up_bn_g + t * MD, up_bn_b + t * MD, MD,
                                             na, nb);
    wscale_kernel<<<208, 256, 0, stream>>>(up_w1 + (size_t)t * MD * HH, na, nb,
                                           up_b1 + t * HH, MD, 96, w1sp, b1c);
    const short* w2t = w2p + (size_t)t * 13 * 7 * 1024;
    const short* w3t = w3p + (size_t)t * 13 * 7 * 1024;
    const short* w4t = w4p + (size_t)t * 4 * 7 * 1024;
    // A/B/C ablation: identical workload per pass, different fused variants
    if (t == 0)
      fused_reg_kernel<false, 8><<<gM128, 512, 0, stream>>>(
          mh, w1sp, w2t, w3t, w4t, b1c, up_b2 + t * HH, up_b3 + t * HH,
          up_b4 + t * ED, x_p, x_q, x_qs, t, nullptr, nullptr, nullptr);
    else if (t == 1)
      fused_reg_kernel<false, 4><<<gM64, 256, 0, stream>>>(
          mh, w1sp, w2t, w3t, w4t, b1c, up_b2 + t * HH, up_b3 + t * HH,
          up_b4 + t * ED, x_p, x_q, x_qs, t, nullptr, nullptr, nullptr);
    else
      fused_dma_kernel<false><<<gM64, 256, 0, stream>>>(
          mh, w1sp, w2t, w3t, w4t, b1c, up_b2 + t * HH, up_b3 + t * HH,
          up_b4 + t * ED, x_p, x_q, x_qs, t, nullptr, nullptr, nullptr);
  }

  colstats_s16_kernel<256><<<NPB2, 256, 0, stream>>>(x_q, P);
  bnfinal2_kernel<<<256, 256, 0, stream>>>(P, NPB2, ro_bn_g, ro_bn_b, RD, na, nb);
  wscale_kernel<<<208, 256, 0, stream>>>(ro_w1, na, nb, ro_b1, RD, 256, r1sp, b1c);
  fused_reg_kernel<true, 4><<<gM64, 256, 0, stream>>>(
      x_q, r1sp, r2p, r3p, nullptr,
      b1c, ro_b2, ro_b3, ro_b4,
      nullptr, nullptr, nullptr, 0, ro_w4, mol, out);

  (void)in_sizes; (void)n_in; (void)out_size; (void)ws_size;
}

// Round 7
// 553.009 us; speedup vs baseline: 1.2642x; 1.2642x over previous
//
#include <hip/hip_runtime.h>
#include <hip/hip_bf16.h>
#include <type_traits>

#define NN 50000
#define NP 50048   // NN padded to 64*782
#define EE 800000
#define TT 3
#define ED 64
#define NS 23
#define MD 87
#define HH 200
#define NMOL 2048
#define RD 256

#define SW 216     // act row stride (shorts): 432B, 16B-aligned, ~2-way banks
#define NPB2 512   // colstats partial blocks
#define SNB ((NN + 255) / 256)  // 196 scan blocks

typedef __attribute__((ext_vector_type(8))) short short8b;
typedef __attribute__((ext_vector_type(4))) float f32x4;

template <int V> using ic = std::integral_constant<int, V>;

// ---- bf16 helpers ----
__device__ __forceinline__ unsigned short f2bf(float f) {
  unsigned u = __float_as_uint(f);
  return (unsigned short)((u + 0x7fffu + ((u >> 16) & 1u)) >> 16);
}
__device__ __forceinline__ float ubf2f(unsigned short h) {
  return __uint_as_float(((unsigned)h) << 16);
}
// interleaved pair in one u32: low16 = hi-bf16, high16 = lo-bf16 (fp32-equivalent)
__device__ __forceinline__ float bfp2f(unsigned p) {
  return __uint_as_float(p << 16) + __uint_as_float(p & 0xffff0000u);
}
__device__ __forceinline__ unsigned packsplit(float v) {
  unsigned short h = f2bf(v);
  unsigned short l = f2bf(v - ubf2f(h));
  return (unsigned)h | ((unsigned)l << 16);
}

// ---------------- weight prep: fp32 [T][K][N] -> PACKED fragment-major planes -----
// Packed layout: per (tile of 16 n-rows, kblk of 32 cols): 1024 shorts =
// [512 hi][512 lo], lane-linear (slot = lane*8+e, lane = quad*16+ln,
// n = tile*16+ln, k = kblk*32+quad*8+e). B-frag load = ONE coalesced 1KB burst.
struct WD { const float* src; short* dst; int K, N, Kpad, Npad, T; };
struct WDs { WD d[5]; };

__global__ __launch_bounds__(256) void wprep_kernel(WDs W) {
  WD w = W.d[blockIdx.y];
  int KB = w.Kpad >> 5, NT = w.Npad >> 4;
  int per = w.Npad * w.Kpad;  // == NT*KB*512
  int total = w.T * per;
  for (int idx = blockIdx.x * 256 + threadIdx.x; idx < total; idx += gridDim.x * 256) {
    int t = idx / per;
    int r = idx - t * per;
    int e = r & 7, lane = (r >> 3) & 63;
    int blk = r >> 9;
    int kb = blk % KB, tile = blk / KB;
    int ln = lane & 15, quad = lane >> 4;
    int n = tile * 16 + ln, k = kb * 32 + quad * 8 + e;
    float v = 0.f;
    if (k < w.K && n < w.N) v = w.src[((size_t)t * w.K + k) * w.N + n];
    unsigned short h = f2bf(v);
    unsigned short l = f2bf(v - ubf2f(h));
    size_t base = ((size_t)(t * NT + tile) * KB + kb) * 1024;
    w.dst[base + lane * 8 + e] = (short)h;
    w.dst[base + 512 + lane * 8 + e] = (short)l;
  }
}

// ---------------- BN-folded layer-1 weight scale (packed output) ----------------
__global__ __launch_bounds__(256) void wscale_kernel(const float* __restrict__ wsrc,
                                                     const float* __restrict__ na,
                                                     const float* __restrict__ nb,
                                                     const float* __restrict__ bsrc,
                                                     int K, int Kpad,
                                                     short* __restrict__ wsp,
                                                     float* __restrict__ bc) {
  int n = blockIdx.x;   // 0..207
  int k = threadIdx.x;  // 0..255
  int KB = Kpad >> 5;
  int tile = n >> 4, ln = n & 15;
  float contrib = 0.f;
  if (k < Kpad) {
    float v = 0.f;
    if (n < HH && k < K) {
      float w = wsrc[(size_t)k * HH + n];
      v = na[k] * w;
      contrib = nb[k] * w;
    }
    unsigned short h = f2bf(v);
    unsigned short l = f2bf(v - ubf2f(h));
    int kb = k >> 5, quad = (k & 31) >> 3, e = k & 7;
    int lane = quad * 16 + ln;
    size_t base = ((size_t)tile * KB + kb) * 1024;
    wsp[base + lane * 8 + e] = (short)h;
    wsp[base + 512 + lane * 8 + e] = (short)l;
  }
  __shared__ float sh[256];
  sh[k] = contrib;
  __syncthreads();
  for (int off = 128; off > 0; off >>= 1) {
    if (k < off) sh[k] += sh[k + off];
    __syncthreads();
  }
  if (k == 0) bc[n] = (n < HH ? bsrc[n] : 0.f) + sh[0];
}

// ---------------- embedding -> x slice 0 (pair + row plane + slice plane) ----
__global__ __launch_bounds__(256) void emb_kernel(const int* __restrict__ z,
                                                  const float* __restrict__ emb,
                                                  unsigned* __restrict__ xp,
                                                  short* __restrict__ xq,
                                                  short* __restrict__ xqs) {
  int idx = blockIdx.x * 256 + threadIdx.x;
  if (idx >= NN * ED) return;
  int i = idx >> 6, d = idx & 63;
  unsigned pk = packsplit(emb[z[i] * ED + d]);
  xp[(size_t)i * RD + d] = pk;
  short h = (short)(pk & 0xffffu);
  xq[(size_t)i * RD + d] = h;
  xqs[(size_t)i * ED + d] = h;  // slice 0
}

// ---------------- CSR build ----------------
__global__ __launch_bounds__(256) void hist_kernel(const int* __restrict__ src,
                                                   int* __restrict__ deg) {
  int e = blockIdx.x * 256 + threadIdx.x;
  if (e < EE) atomicAdd(&deg[src[e]], 1);
}

// 3-stage parallel exclusive scan of deg[0..NN)
__global__ __launch_bounds__(256) void scanA_kernel(const int* __restrict__ deg,
                                                    int* __restrict__ Psum) {
  int i = blockIdx.x * 256 + threadIdx.x;
  int v = (i < NN) ? deg[i] : 0;
#pragma unroll
  for (int off = 32; off > 0; off >>= 1) v += __shfl_down(v, off, 64);
  __shared__ int ws[4];
  if ((threadIdx.x & 63) == 0) ws[threadIdx.x >> 6] = v;
  __syncthreads();
  if (threadIdx.x == 0) Psum[blockIdx.x] = ws[0] + ws[1] + ws[2] + ws[3];
}

__global__ __launch_bounds__(256) void scanB_kernel(const int* __restrict__ Psum,
                                                    int* __restrict__ Poff) {
  __shared__ int sh[256];
  int t = threadIdx.x;
  int v = (t < SNB) ? Psum[t] : 0;
  sh[t] = v;
  __syncthreads();
  for (int off = 1; off < 256; off <<= 1) {
    int u = (t >= off) ? sh[t - off] : 0;
    __syncthreads();
    sh[t] += u;
    __syncthreads();
  }
  if (t < SNB) Poff[t] = sh[t] - v;  // exclusive
}

__global__ __launch_bounds__(256) void scanC_kernel(const int* __restrict__ deg,
                                                    const int* __restrict__ Poff,
                                                    int* __restrict__ offs,
                                                    int* __restrict__ cursor) {
  __shared__ int sh[256];
  int t = threadIdx.x;
  int i = blockIdx.x * 256 + t;
  int v = (i < NN) ? deg[i] : 0;
  sh[t] = v;
  __syncthreads();
  for (int off = 1; off < 256; off <<= 1) {
    int u = (t >= off) ? sh[t - off] : 0;
    __syncthreads();
    sh[t] += u;
    __syncthreads();
  }
  int excl = Poff[blockIdx.x] + sh[t] - v;
  if (i < NN) {
    offs[i] = excl;
    cursor[i] = excl;
    if (i == NN - 1) offs[NN] = excl + v;
  }
}

__global__ __launch_bounds__(256) void scatter_kernel(const int* __restrict__ src,
                                                      const int* __restrict__ snk,
                                                      const float* __restrict__ dist,
                                                      int* __restrict__ cursor,
                                                      int* __restrict__ ssink,
                                                      float* __restrict__ sdist) {
  int e = blockIdx.x * 256 + threadIdx.x;
  if (e >= EE) return;
  int p = atomicAdd(&cursor[src[e]], 1);
  ssink[p] = snk[e];
  sdist[p] = dist[e];
}

// ---------------- message gather: one wave per node ----------------
template <bool RBF>
__global__ __launch_bounds__(256) void gather_kernel(const int* __restrict__ offs,
                                                     const int* __restrict__ ssink,
                                                     const float* __restrict__ sdist,
                                                     const short* __restrict__ xqs,
                                                     short* __restrict__ mh) {
  int node = blockIdx.x * 4 + (threadIdx.x >> 6);
  int lane = threadIdx.x & 63;
  if (node >= NN) return;
  float shift = (float)(0.8 + 0.1 * (double)lane);
  int e0 = offs[node], e1 = offs[node + 1];
  float ax0 = 0.f, ax1 = 0.f, ar0 = 0.f, ar1 = 0.f;
  int j = e0;
  for (; j + 4 <= e1; j += 4) {
    int s0 = ssink[j], s1 = ssink[j + 1], s2 = ssink[j + 2], s3 = ssink[j + 3];
    float x0 = ubf2f((unsigned short)xqs[(size_t)s0 * ED + lane]);
    float x1 = ubf2f((unsigned short)xqs[(size_t)s1 * ED + lane]);
    float x2 = ubf2f((unsigned short)xqs[(size_t)s2 * ED + lane]);
    float x3 = ubf2f((unsigned short)xqs[(size_t)s3 * ED + lane]);
    ax0 += x0 + x2;
    ax1 += x1 + x3;
    if (RBF && lane < NS) {
      float d0 = sdist[j], d1 = sdist[j + 1], d2 = sdist[j + 2], d3 = sdist[j + 3];
      float u0 = d0 - shift, u1 = d1 - shift, u2 = d2 - shift, u3 = d3 - shift;
      ar0 += __expf(-u0 * u0) + __expf(-u2 * u2);
      ar1 += __expf(-u1 * u1) + __expf(-u3 * u3);
    }
  }
  for (; j < e1; j++) {
    int s = ssink[j];
    ax0 += ubf2f((unsigned short)xqs[(size_t)s * ED + lane]);
    if (RBF && lane < NS) {
      float u = sdist[j] - shift;
      ar0 += __expf(-u * u);
    }
  }
  float accx = ax0 + ax1;
  if (RBF && lane < NS) mh[(size_t)node * 96 + lane] = (short)f2bf(ar0 + ar1);
  if (RBF && lane >= NS && lane < 32) mh[(size_t)node * 96 + 64 + lane] = 0;
  mh[(size_t)node * 96 + NS + lane] = (short)f2bf(accx);
}

// ---------------- batchnorm stats on bf16 planes (vectorized, 512 blocks) ----
template <int LD>
__global__ __launch_bounds__(256) void colstats_s16_kernel(const short* __restrict__ X,
                                                           float* __restrict__ P) {
  constexpr int CG = LD / 8;     // 8-col groups
  constexpr int RPB = 256 / CG;
  const int t = threadIdx.x;
  const int cg = t % CG, rin = t / CG;
  float s[8] = {0, 0, 0, 0, 0, 0, 0, 0}, q[8] = {0, 0, 0, 0, 0, 0, 0, 0};
  if (rin < RPB) {
    for (int r = blockIdx.x * RPB + rin; r < NN; r += gridDim.x * RPB) {
      union { uint4 v; short e[8]; } u;
      u.v = *(const uint4*)(X + (size_t)r * LD + cg * 8);
#pragma unroll
      for (int e = 0; e < 8; e++) {
        float f = ubf2f((unsigned short)u.e[e]);
        s[e] += f;
        q[e] += f * f;
      }
    }
  }
  __shared__ float sh[256][16];
#pragma unroll
  for (int e = 0; e < 8; e++) { sh[t][e] = s[e]; sh[t][8 + e] = q[e]; }
  __syncthreads();
  if (rin == 0) {
    for (int rr = 1; rr < RPB; rr++) {
      const float* o = sh[rr * CG + cg];
#pragma unroll
      for (int e = 0; e < 8; e++) { s[e] += o[e]; q[e] += o[8 + e]; }
    }
    float* Pb = P + blockIdx.x * 512;
#pragma unroll
    for (int e = 0; e < 8; e++) {
      Pb[cg * 8 + e] = s[e];
      Pb[256 + cg * 8 + e] = q[e];
    }
  }
}

// ---------------- batchnorm stats: stage 2 (one block per column) ------------
__global__ __launch_bounds__(256) void bnfinal2_kernel(const float* __restrict__ P, int nblk,
                                                       const float* __restrict__ g,
                                                       const float* __restrict__ b, int ncols,
                                                       float* __restrict__ na,
                                                       float* __restrict__ nb) {
  int c = blockIdx.x;
  int t = threadIdx.x;
  float s = 0.f, q = 0.f;
  for (int i = t; i < nblk; i += 256) {
    s += P[i * 512 + c];
    q += P[i * 512 + 256 + c];
  }
#pragma unroll
  for (int off = 32; off > 0; off >>= 1) {
    s += __shfl_down(s, off, 64);
    q += __shfl_down(q, off, 64);
  }
  __shared__ float ws[4], wq[4];
  if ((t & 63) == 0) { ws[t >> 6] = s; wq[t >> 6] = q; }
  __syncthreads();
  if (t == 0) {
    s = ws[0] + ws[1] + ws[2] + ws[3];
    q = wq[0] + wq[1] + wq[2] + wq[3];
    if (c < ncols) {
      float mean = s / (float)NN;
      float var = q / (float)NN - mean * mean;
      float a = g[c] * rsqrtf(var + 1e-5f);
      na[c] = a;
      nb[c] = b[c] - mean * a;
    } else {
      na[c] = 0.f;
      nb[c] = 0.f;
    }
  }
}

// ---------------- fused MLP kernel (R26: B-in-registers, barrier-light) ------
// 4 waves x 64 shared rows. Each wave loads ITS layer's B-fragments (owned
// n-tiles {w,w+4,w+8,w+12}) into REGISTERS once per layer (<=28 x 16B burst),
// then the k-loop is pure ds_read(A from act plane) + MFMA: no loads, no
// barriers inside. 5 raw barriers/block total; next layer's B-burst is issued
// BEFORE the raw s_barrier+lgkmcnt(0) (no vmcnt drain -> stays in flight, T4).
template <bool READOUT>
__global__ __launch_bounds__(256, 2) void fused_kernel(
    const short* __restrict__ Agh,
    const short* __restrict__ W1p, const short* __restrict__ W2p,
    const short* __restrict__ W3p, const short* __restrict__ W4p,
    const float* __restrict__ b1, const float* __restrict__ b2,
    const float* __restrict__ b3, const float* __restrict__ b4,
    unsigned* __restrict__ xp, short* __restrict__ xq, short* __restrict__ xqs,
    int t, const float* __restrict__ w4ro, const int* __restrict__ mol,
    float* __restrict__ out) {
  __shared__ short act[64 * SW];           // 27648 B
  constexpr int GLDA = READOUT ? RD : 96;  // L1 A row stride (x_q / mh)
  constexpr int KB1 = READOUT ? 8 : 3;     // L1 K blocks
  constexpr int NB = READOUT ? 32 : 28;    // Breg slots (16B each)
  const int tid = threadIdx.x;
  const int wave = tid >> 6, lane = tid & 63, ln = lane & 15, quad = lane >> 4;
  const int q8 = quad * 8;
  const int bm = blockIdx.x * 64;

  // zero K-pad cols [208,216): read as A k-pad (garbage bf16 could be NaN)
  *(unsigned*)(act + (tid >> 2) * SW + 208 + (tid & 3) * 2) = 0u;

  f32x4 acc[4][4];     // [owned-tile j][row-tile i]
  short8b Breg[NB];    // layer-resident B fragments
  const short8b zfrag = {0, 0, 0, 0, 0, 0, 0, 0};

  // burst-load this wave's B frags for SL slices of a layer (KBfull = packed
  // k-stride; kb0 = k-block offset for split-K readout L1)
  auto loadB = [&](auto slt, auto tmt, auto ntt, const short* __restrict__ Wp,
                   int KBfull, int kb0) {
    constexpr int SL = decltype(slt)::value;
    constexpr int TM = decltype(tmt)::value;
    constexpr int NT = decltype(ntt)::value;
#pragma unroll
    for (int j = 0; j < 4; j++) {
      int tile = wave + 4 * j;
      if (tile < NT) {
#pragma unroll
        for (int s = 0; s < SL; s++) {
          int kb = kb0 + ((TM == 2) ? (s >> 1) : s);
          int pl = (TM == 2) ? ((s & 1) << 9) : 0;
          Breg[j * SL + s] = *(const short8b*)(
              Wp + (size_t)(tile * KBfull + kb) * 1024 + pl + lane * 8);
        }
      }
    }
  };

  // k-loop: A from global (GA, L1) or act plane; B from Breg; acc += A*B
  auto mfmaloop = [&](auto slt, auto tmt, auto ntt, auto gat, auto rstt, int kb0) {
    constexpr int SL = decltype(slt)::value;
    constexpr int TM = decltype(tmt)::value;
    constexpr int NT = decltype(ntt)::value;
    constexpr bool GA = decltype(gat)::value;
    constexpr bool RST = decltype(rstt)::value;
    constexpr int KB = SL / TM;
    if constexpr (RST) {
#pragma unroll
      for (int j = 0; j < 4; j++)
#pragma unroll
        for (int i = 0; i < 4; i++) acc[j][i] = (f32x4){0.f, 0.f, 0.f, 0.f};
    }
#pragma unroll
    for (int kb = 0; kb < KB; kb++) {
      int col = (kb0 + kb) * 32 + q8;
      short8b a[4];
#pragma unroll
      for (int i = 0; i < 4; i++) {
        if constexpr (GA)
          a[i] = *(const short8b*)(Agh + (size_t)(bm + i * 16 + ln) * GLDA + col);
        else
          a[i] = (col < 216) ? *(const short8b*)(act + (i * 16 + ln) * SW + col)
                             : zfrag;
      }
#pragma unroll
      for (int s2 = 0; s2 < TM; s2++)
#pragma unroll
        for (int j = 0; j < 4; j++) {
          int tile = wave + 4 * j;
          if (tile < NT) {
#pragma unroll
            for (int i = 0; i < 4; i++)
              acc[j][i] = __builtin_amdgcn_mfma_f32_16x16x32_bf16(
                  a[i], Breg[j * SL + kb * TM + s2], acc[j][i], 0, 0, 0);
          }
        }
    }
  };

  // relu(acc+bias) -> act plane (D layout: col=ln, row=quad*4+r)
  auto epi = [&](const float* __restrict__ bias) {
#pragma unroll
    for (int j = 0; j < 4; j++) {
      int tile = wave + 4 * j;
      if (tile < 13) {
        int colg = tile * 16 + ln;
        float bb = (colg < HH) ? bias[colg] : 0.f;
#pragma unroll
        for (int i = 0; i < 4; i++)
#pragma unroll
          for (int r = 0; r < 4; r++)
            act[(i * 16 + quad * 4 + r) * SW + colg] =
                (short)f2bf(fmaxf(acc[j][i][r] + bb, 0.f));
      }
    }
  };

  // raw barrier (no vmcnt drain): in-flight global B-bursts survive
  auto bar = [] {
    __builtin_amdgcn_sched_barrier(0);
    __builtin_amdgcn_s_barrier();
    __builtin_amdgcn_sched_barrier(0);
  };
  // publish LDS writes, then raw barrier
  auto lgkmbar = [] {
    asm volatile("s_waitcnt lgkmcnt(0)" ::: "memory");
    __builtin_amdgcn_sched_barrier(0);
    __builtin_amdgcn_s_barrier();
    __builtin_amdgcn_sched_barrier(0);
  };

  using T = std::true_type;
  using F = std::false_type;

  // ---- L1 (A from global) ----
  if constexpr (!READOUT) {
    loadB(ic<6>{}, ic<2>{}, ic<13>{}, W1p, KB1, 0);
    mfmaloop(ic<6>{}, ic<2>{}, ic<13>{}, T{}, T{}, 0);
  } else {
    loadB(ic<8>{}, ic<2>{}, ic<13>{}, W1p, KB1, 0);   // kb 0..3
    mfmaloop(ic<8>{}, ic<2>{}, ic<13>{}, T{}, T{}, 0);
    loadB(ic<8>{}, ic<2>{}, ic<13>{}, W1p, KB1, 4);   // kb 4..7
    mfmaloop(ic<8>{}, ic<2>{}, ic<13>{}, T{}, F{}, 4);
  }
  loadB(ic<7>{}, ic<1>{}, ic<13>{}, W2p, 7, 0);  // L2 B-burst, in flight across barrier
  epi(b1);
  lgkmbar();

  // ---- L2 ----
  mfmaloop(ic<7>{}, ic<1>{}, ic<13>{}, F{}, T{}, 0);
  loadB(ic<7>{}, ic<1>{}, ic<13>{}, W3p, 7, 0);  // L3 B-burst
  bar();       // all act reads done
  epi(b2);
  lgkmbar();

  // ---- L3 ----
  mfmaloop(ic<7>{}, ic<1>{}, ic<13>{}, F{}, T{}, 0);
  if constexpr (!READOUT)
    loadB(ic<14>{}, ic<2>{}, ic<4>{}, W4p, 7, 0);  // L4 B-burst
  bar();
  epi(b3);
  lgkmbar();

  if constexpr (!READOUT) {
    // ---- L4 (224->64, 2-term); wave owns tile==wave -> acc[0] ----
    mfmaloop(ic<14>{}, ic<2>{}, ic<4>{}, F{}, T{}, 0);
    int colg = wave * 16 + ln;
    float bb = b4[colg];
#pragma unroll
    for (int i = 0; i < 4; i++)
#pragma unroll
      for (int r = 0; r < 4; r++) {
        int grow = bm + i * 16 + quad * 4 + r;
        if (grow < NN) {
          size_t base = (size_t)grow * RD;
          float oldv = bfp2f(xp[base + (size_t)t * ED + colg]);
          unsigned pk = packsplit(oldv + 0.1f * (acc[0][i][r] + bb));
          xp[base + (size_t)(t + 1) * ED + colg] = pk;
          short h = (short)(pk & 0xffffu);
          xq[base + (size_t)(t + 1) * ED + colg] = h;
          xqs[(size_t)(t + 1) * NN * ED + (size_t)grow * ED + colg] = h;
        }
      }
  } else {
    // ---- final 200->1 + molecule segment-sum: 4 threads per row ----
    int row = tid >> 2;
    float s = 0.f;
    for (int c = (tid & 3); c < HH; c += 4)
      s += ubf2f((unsigned short)act[row * SW + c]) * w4ro[c];
    s += __shfl_xor(s, 1, 64);
    s += __shfl_xor(s, 2, 64);
    int grow = bm + row;
    if ((tid & 3) == 0 && grow < NN) atomicAdd(&out[mol[grow]], s + b4[0]);
  }
}

// ---------------- host launcher ----------------
extern "C" void kernel_launch(void* const* d_in, const int* in_sizes, int n_in,
                              void* d_out, int out_size, void* d_ws, size_t ws_size,
                              hipStream_t stream) {
  const int* z_i = (const int*)d_in[0];
  const int* e_src = (const int*)d_in[1];
  const int* e_snk = ((const int*)d_in[1]) + EE;
  const float* dist = (const float*)d_in[2];
  const int* mol = (const int*)d_in[3];
  const float* emb = (const float*)d_in[4];
  const float* up_bn_g = (const float*)d_in[5];
  const float* up_bn_b = (const float*)d_in[6];
  const float* up_w1 = (const float*)d_in[7];
  const float* up_b1 = (const float*)d_in[8];
  const float* up_w2 = (const float*)d_in[9];
  const float* up_b2 = (const float*)d_in[10];
  const float* up_w3 = (const float*)d_in[11];
  const float* up_b3 = (const float*)d_in[12];
  const float* up_w4 = (const float*)d_in[13];
  const float* up_b4 = (const float*)d_in[14];
  const float* ro_bn_g = (const float*)d_in[15];
  const float* ro_bn_b = (const float*)d_in[16];
  const float* ro_w1 = (const float*)d_in[17];
  const float* ro_b1 = (const float*)d_in[18];
  const float* ro_w2 = (const float*)d_in[19];
  const float* ro_b2 = (const float*)d_in[20];
  const float* ro_w3 = (const float*)d_in[21];
  const float* ro_b3 = (const float*)d_in[22];
  const float* ro_w4 = (const float*)d_in[23];
  const float* ro_b4 = (const float*)d_in[24];
  float* out = (float*)d_out;

  char* p = (char*)d_ws;
  auto alloc = [&](size_t bytes) {
    void* r = (void*)p;
    p += (bytes + 255) & ~(size_t)255;
    return r;
  };
  unsigned* x_p = (unsigned*)alloc((size_t)NN * RD * 4);     // fp32-equiv pair
  short* x_q = (short*)alloc((size_t)NP * RD * 2);           // x hi plane (row-major)
  short* x_qs = (short*)alloc((size_t)(TT + 1) * NN * ED * 2);  // x hi SLICE-major (gather)
  short* mh = (short*)alloc((size_t)NP * 96 * 2);            // raw m hi plane
  int* ssink = (int*)alloc((size_t)EE * 4);
  float* sdist = (float*)alloc((size_t)EE * 4);
  int* offs = (int*)alloc((size_t)(NN + 1) * 4);
  int* deg = (int*)alloc((size_t)NN * 4);
  int* cursor = (int*)alloc((size_t)NN * 4);
  int* Psum = (int*)alloc((size_t)SNB * 4);
  int* Poff = (int*)alloc((size_t)SNB * 4);
  float* P = (float*)alloc((size_t)NPB2 * 512 * 4);
  float* na = (float*)alloc(256 * 4);
  float* nb = (float*)alloc(256 * 4);
  float* b1c = (float*)alloc(208 * 4);
  // packed layer-1 (BN-scaled per pass / readout)
  short* w1sp = (short*)alloc((size_t)13 * 3 * 1024 * 2);
  short* r1sp = (short*)alloc((size_t)13 * 8 * 1024 * 2);
  // packed static weights
  short* w2p = (short*)alloc((size_t)TT * 13 * 7 * 1024 * 2);
  short* w3p = (short*)alloc((size_t)TT * 13 * 7 * 1024 * 2);
  short* w4p = (short*)alloc((size_t)TT * 4 * 7 * 1024 * 2);
  short* r2p = (short*)alloc((size_t)13 * 7 * 1024 * 2);
  short* r3p = (short*)alloc((size_t)13 * 7 * 1024 * 2);

  hipMemsetAsync(deg, 0, (size_t)NN * 4, stream);
  hipMemsetAsync(out, 0, (size_t)NMOL * 4, stream);

  WDs descs;
  descs.d[0] = {up_w2, w2p, HH, HH, 224, 208, TT};
  descs.d[1] = {up_w3, w3p, HH, HH, 224, 208, TT};
  descs.d[2] = {up_w4, w4p, HH, ED, 224, 64, TT};
  descs.d[3] = {ro_w2, r2p, HH, HH, 224, 208, 1};
  descs.d[4] = {ro_w3, r3p, HH, HH, 224, 208, 1};
  wprep_kernel<<<dim3(546, 5), 256, 0, stream>>>(descs);

  emb_kernel<<<(NN * ED + 255) / 256, 256, 0, stream>>>(z_i, emb, x_p, x_q, x_qs);
  hist_kernel<<<(EE + 255) / 256, 256, 0, stream>>>(e_src, deg);
  scanA_kernel<<<SNB, 256, 0, stream>>>(deg, Psum);
  scanB_kernel<<<1, 256, 0, stream>>>(Psum, Poff);
  scanC_kernel<<<SNB, 256, 0, stream>>>(deg, Poff, offs, cursor);
  scatter_kernel<<<(EE + 255) / 256, 256, 0, stream>>>(e_src, e_snk, dist, cursor, ssink, sdist);

  const int gM = NP / 64;  // 782 blocks x 4 waves, 64 shared rows

  for (int t = 0; t < TT; t++) {
    if (t == 0)
      gather_kernel<true><<<(NN + 3) / 4, 256, 0, stream>>>(
          offs, ssink, sdist, x_qs, mh);
    else
      gather_kernel<false><<<(NN + 3) / 4, 256, 0, stream>>>(
          offs, ssink, sdist, x_qs + (size_t)t * NN * ED, mh);
    colstats_s16_kernel<96><<<NPB2, 256, 0, stream>>>(mh, P);
    bnfinal2_kernel<<<256, 256, 0, stream>>>(P, NPB2, up_bn_g + t * MD, up_bn_b + t * MD, MD,
                                             na, nb);
    wscale_kernel<<<208, 256, 0, stream>>>(up_w1 + (size_t)t * MD * HH, na, nb,
                                           up_b1 + t * HH, MD, 96, w1sp, b1c);
    fused_kernel<false><<<gM, 256, 0, stream>>>(
        mh, w1sp,
        w2p + (size_t)t * 13 * 7 * 1024, w3p + (size_t)t * 13 * 7 * 1024,
        w4p + (size_t)t * 4 * 7 * 1024,
        b1c, up_b2 + t * HH, up_b3 + t * HH, up_b4 + t * ED,
        x_p, x_q, x_qs, t, nullptr, nullptr, nullptr);
  }

  colstats_s16_kernel<256><<<NPB2, 256, 0, stream>>>(x_q, P);
  bnfinal2_kernel<<<256, 256, 0, stream>>>(P, NPB2, ro_bn_g, ro_bn_b, RD, na, nb);
  wscale_kernel<<<208, 256, 0, stream>>>(ro_w1, na, nb, ro_b1, RD, 256, r1sp, b1c);
  fused_kernel<true><<<gM, 256, 0, stream>>>(
      x_q, r1sp, r2p, r3p, nullptr,
      b1c, ro_b2, ro_b3, ro_b4,
      nullptr, nullptr, nullptr, 0, ro_w4, mol, out);

  (void)in_sizes; (void)n_in; (void)out_size; (void)ws_size;
}